// Round 14
// baseline (27.778 us; speedup 1.0000x reference)
//
#include <hip/hip_runtime.h>
#include <math.h>

#define HH 384
#define WW 384
#define HWSZ (HH * WW)
#define NPIX (2 * HWSZ)
#define KSEL 11
#define TW 48                  // tile width
#define TH 4                   // tile height
#define PXB (TW * TH)          // 192 interior px per block
#define NTHR 128               // 2 waves
#define NW 2
#define TPW (TW + 10)          // 58
#define TPH (TH + 10)          // 14
#define TILE_N (TPW * TPH)     // 812 float4 (~13 KB)
#define NTASK ((TILE_N + NTHR - 1) / NTHR)  // 7
#define NBX (WW / TW)          // 8
#define NBY (HH / TH)          // 96
#define NBLK (2 * NBX * NBY)   // 1536 = exactly 6 blocks/CU
#define NGROUP (NBLK * NW)     // 3072 partial groups

__device__ __forceinline__ float fast_sqrtf(float x) {
    float r;
    asm("v_sqrt_f32 %0, %1" : "=v"(r) : "v"(x));
    return r;
}

__device__ __forceinline__ float wave_sum(float v) {
#pragma unroll
    for (int off = 32; off > 0; off >>= 1) v += __shfl_down(v, off, 64);
    return v;
}

// Key: high 20 bits = d^2 (f32 bits truncated), low 12 = pre-quantized
// neighbor alpha. d2 >= 0 so float min/max order == lexicographic.
__device__ __forceinline__ float make_key(const float4 c, const float4 n) {
    const float e0 = c.x - n.x;
    const float e1 = c.y - n.y;
    const float e2 = c.z - n.z;
    float d2 = e0 * e0;
    d2 = __builtin_fmaf(e1, e1, d2);
    d2 = __builtin_fmaf(e2, e2, d2);
    const unsigned bits = (__float_as_uint(d2) & 0xFFFFF000u) | __float_as_uint(n.w);
    return __uint_as_float(bits);
}

__device__ __forceinline__ void merge2(float bd[KSEL], float a, float b) {
    const float p0 = fminf(a, b);
    const float p1 = fmaxf(a, b);
    float nb[KSEL];
    nb[0] = fminf(bd[0], p0);
    nb[1] = fminf(fminf(bd[1], fmaxf(bd[0], p0)), p1);
#pragma unroll
    for (int j = 2; j < KSEL; ++j)
        nb[j] = fminf(fminf(bd[j], fmaxf(bd[j - 1], p0)), fmaxf(bd[j - 2], p1));
#pragma unroll
    for (int j = 0; j < KSEL; ++j) bd[j] = nb[j];
}

__device__ __forceinline__ void merge1(float bd[KSEL], float p) {
    float cd = p;
#pragma unroll
    for (int j = 0; j < KSEL; ++j) {
        const float mx = fmaxf(cd, bd[j]);
        bd[j] = fminf(cd, bd[j]);
        cd = mx;
    }
}

__device__ __forceinline__ float acc_ddc(const float bd[KSEL], float ac) {
    float s = 0.f;
#pragma unroll
    for (int j = 0; j < KSEL; ++j) {
        const unsigned kb = __float_as_uint(bd[j]);
        const float d2 = __uint_as_float((kb & 0xFFFFF000u) | 0x800u); // midpoint
        const float ad = __builtin_fmaf((float)(kb & 0xFFFu), -1.0f / 4095.0f, ac);
        s += fabsf(fast_sqrtf(d2) - ad);
    }
    return s;
}

#define LOAD_ROW(DST, DI)                                   \
    _Pragma("unroll") for (int h_ = 0; h_ < 11; ++h_)       \
        DST[h_] = tp[(DI) * TPW + h_];

#define PROC_ROW(SRC)                                       \
    {                                                       \
        float k_[11];                                       \
        _Pragma("unroll") for (int h_ = 0; h_ < 11; ++h_)   \
            k_[h_] = make_key(c4, SRC[h_]);                 \
        _Pragma("unroll") for (int h_ = 0; h_ < 5; ++h_)    \
            merge2(bd, k_[2 * h_], k_[2 * h_ + 1]);         \
        merge1(bd, k_[10]);                                 \
    }

__global__ __launch_bounds__(NTHR, 2) void matting_main(
    const float* __restrict__ alpha,
    const float* __restrict__ trimap,
    const float* __restrict__ image,
    float* __restrict__ ws)
{
    __shared__ float4 tile[TILE_N];            // denorm rgb + quantized-alpha
    __shared__ float aex[PXB];                 // exact alpha, interior px
    __shared__ unsigned short list[PXB];       // compacted unknown px
    __shared__ unsigned long long chMask[3];   // per-64-chunk ballot masks

    const int tid = (int)threadIdx.x;
    const int lane = tid & 63;
    const int w    = tid >> 6;
    const int bx  = blockIdx.x % NBX;
    const int byy = (blockIdx.x / NBX) % NBY;
    const int b   = blockIdx.x / (NBX * NBY);

    const float* i0 = image + b * 3 * HWSZ;
    const float* i1 = i0 + HWSZ;
    const float* i2 = i1 + HWSZ;
    const float* ap = alpha + b * HWSZ;
    const float* tm = trimap + b * HWSZ;

    const int row0 = byy * TH, col0 = bx * TW;
    const int gy0 = row0 - 5, gx0 = col0 - 5;

    // ---- Phase A: issue ALL cold global loads up-front (branch-free,
    // clamped addresses + mask) so ~30 misses/wave are in flight at once.
    float rv[NTASK], gv[NTASK], bv[NTASK], av[NTASK];
    bool okm[NTASK];
    int tt[NTASK];
#pragma unroll
    for (int it = 0; it < NTASK; ++it) {
        int t = it * NTHR + tid;
        const bool valid = t < TILE_N;
        t = valid ? t : TILE_N - 1;
        tt[it] = valid ? t : -1;
        const int ry = t / TPW, rx = t - ry * TPW;
        const int gy = gy0 + ry, gx = gx0 + rx;
        const bool ok = ((unsigned)gy < (unsigned)HH) && ((unsigned)gx < (unsigned)WW);
        okm[it] = ok;
        const int gyc = min(max(gy, 0), HH - 1);
        const int gxc = min(max(gx, 0), WW - 1);
        const int gi = gyc * WW + gxc;
        rv[it] = i0[gi]; gv[it] = i1[gi]; bv[it] = i2[gi]; av[it] = ap[gi];
    }
    float trv[2], aiv[2];
#pragma unroll
    for (int q = 0; q < 2; ++q) {
        int p = q * NTHR + tid;
        const bool v = p < PXB;
        p = v ? p : 0;
        const int r = p / TW, c = p - r * TW;
        const int gi = (row0 + r) * WW + col0 + c;
        trv[q] = tm[gi];              // trimap's ONLY (cold) read
        aiv[q] = ap[gi];              // L1-hot (read in batch above)
    }
    __builtin_amdgcn_sched_barrier(0);

    // ---- Phase B: write tile ----
#pragma unroll
    for (int it = 0; it < NTASK; ++it) {
        if (tt[it] >= 0) {
            float4 v;
            const bool ok = okm[it];
            v.x = ok ? __builtin_fmaf(rv[it], 0.229f, 0.485f) : 0.f;
            v.y = ok ? __builtin_fmaf(gv[it], 0.224f, 0.456f) : 0.f;
            v.z = ok ? __builtin_fmaf(bv[it], 0.225f, 0.406f) : 0.f;
            v.w = ok ? __uint_as_float((unsigned)(av[it] * 4095.0f)) : 0.f;
            tile[tt[it]] = v;
        }
    }

    // ---- compaction ballots (chunk q*128+tid -> chunks {w, 2}) + known-L1 ----
    float kv = 0.f;
    float unkc = 0.f, pxc = 0.f;
#pragma unroll
    for (int q = 0; q < 2; ++q) {
        const int p = q * NTHR + tid;
        const bool in = p < PXB;
        const bool unk = in && (trv[q] == 0.5f);
        if (in) aex[p] = aiv[q];
        kv += (in && trv[q] != 0.5f) ? fabsf(aiv[q] - trv[q]) : 0.f;
        unkc += unk ? 1.f : 0.f;
        pxc  += in ? 1.f : 0.f;
        const unsigned long long m = __ballot(unk);
        const int chunk = q * 2 + w;                 // 0,1 then 2,(3 invalid)
        if (lane == 0 && chunk < 3) chMask[chunk] = m;
    }
    __syncthreads();

    // ---- deterministic scatter ----
    const unsigned c0 = (unsigned)__popcll(chMask[0]);
    const unsigned c1 = (unsigned)__popcll(chMask[1]);
    const unsigned c2 = (unsigned)__popcll(chMask[2]);
    const unsigned cnt = c0 + c1 + c2;
    {
        const unsigned preA[3] = {0u, c0, c0 + c1};
#pragma unroll
        for (int q = 0; q < 2; ++q) {
            const int chunk = q * 2 + w;
            if (chunk < 3) {
                const unsigned long long m = chMask[chunk];
                if ((m >> lane) & 1ull) {
                    const int p = q * NTHR + tid;
                    const int r = p / TW, c = p - r * TW;
                    list[preA[chunk] +
                         (unsigned)__popcll(m & ((1ull << lane) - 1ull))] =
                        (unsigned short)((r << 6) | c);
                }
            }
        }
    }
    __syncthreads();

    // ---- selection: waves claim alternating 64-chunks of the block list ----
    float wdsum = 0.f;
    for (unsigned start = (unsigned)w * 64u; start < cnt; start += 128u) {
        const unsigned i = start + (unsigned)lane;
        const bool act = i < cnt;
        if (act) {
            const unsigned e = (unsigned)list[i];
            const int r = (int)(e >> 6), cc = (int)(e & 63u);

            const float4* tp = &tile[r * TPW + cc];
            const float4 c4 = tp[5 * TPW + 5];
            const float ac = aex[r * TW + cc];

            float bd[KSEL];
#pragma unroll
            for (int j = 0; j < KSEL; ++j) bd[j] = __uint_as_float(0x7F800000u);

            float4 A_[11], B_[11];
            LOAD_ROW(A_, 0)
            LOAD_ROW(B_, 1)
            __builtin_amdgcn_sched_barrier(0);
#pragma unroll
            for (int dd = 0; dd < 5; ++dd) {
                PROC_ROW(A_)
                if (2 * dd + 2 < 11) LOAD_ROW(A_, 2 * dd + 2)
                __builtin_amdgcn_sched_barrier(0);
                PROC_ROW(B_)
                if (2 * dd + 3 < 11) LOAD_ROW(B_, 2 * dd + 3)
                __builtin_amdgcn_sched_barrier(0);
            }
            PROC_ROW(A_)   // row 10

            wdsum += acc_ddc(bd, ac);
        }
    }

    // ---- per-wave partials ----
    const float vkv = wave_sum(kv);
    const float vds = wave_sum(wdsum);
    const float vun = wave_sum(unkc);
    const float vpx = wave_sum(pxc);
    if (lane == 0) {
        float* g = ws + (blockIdx.x * NW + w) * 4;
        g[0] = vkv;
        g[1] = vpx - vun;      // known count (this wave's px)
        g[2] = vds;
        g[3] = vun;            // unknown count
    }
}

__global__ __launch_bounds__(256) void matting_finalize(
    const float* __restrict__ ws, float* __restrict__ out)
{
    float a = 0, b = 0, c = 0, d = 0;
    for (int i = threadIdx.x; i < NGROUP; i += 256) {
        a += ws[i * 4 + 0];
        b += ws[i * 4 + 1];
        c += ws[i * 4 + 2];
        d += ws[i * 4 + 3];
    }
    a = wave_sum(a); b = wave_sum(b); c = wave_sum(c); d = wave_sum(d);
    __shared__ float sred[4][4];
    const int wid = threadIdx.x >> 6, lane = threadIdx.x & 63;
    if (lane == 0) { sred[wid][0] = a; sred[wid][1] = b; sred[wid][2] = c; sred[wid][3] = d; }
    __syncthreads();
    if (threadIdx.x == 0) {
        float ksum = 0, kcnt = 0, dsum = 0, scnt = 0;
#pragma unroll
        for (int q = 0; q < 4; ++q) {
            ksum += sred[q][0]; kcnt += sred[q][1]; dsum += sred[q][2]; scnt += sred[q][3];
        }
        const float known = (kcnt > 0.f) ? ksum * (1.0f / (float)NPIX) : 0.f;
        const float ddc   = (scnt > 0.f) ? dsum * (0.1f / ((float)NPIX * (float)KSEL)) : 0.f;
        out[0] = known + ddc;
        out[1] = known;
        out[2] = ddc;
    }
}

extern "C" void kernel_launch(void* const* d_in, const int* in_sizes, int n_in,
                              void* d_out, int out_size, void* d_ws, size_t ws_size,
                              hipStream_t stream) {
    const float* alpha  = (const float*)d_in[0];  // pred_alpha  [2,1,384,384]
    const float* trimap = (const float*)d_in[1];  // gt_trimap   [2,1,384,384]
    const float* image  = (const float*)d_in[2];  // input_image [2,3,384,384]
    float* out = (float*)d_out;
    float* ws  = (float*)d_ws;                    // NGROUP*4 floats

    matting_main<<<NBLK, NTHR, 0, stream>>>(alpha, trimap, image, ws);
    matting_finalize<<<1, 256, 0, stream>>>(ws, out);
}